// Round 1
// baseline (1007.664 us; speedup 1.0000x reference)
//
#include <hip/hip_runtime.h>
#include <hip/hip_bf16.h>

typedef __attribute__((ext_vector_type(8))) short short8;
typedef __attribute__((ext_vector_type(4))) float floatx4;
typedef unsigned short u16;

#define T_SZ 609
#define K1V  4872   // valid K of flattened LSTM output (609*8)
#define K1P  4896   // padded to multiple of 32

static __device__ __forceinline__ u16 f2bf(float f) {
    union { float f; unsigned u; } a; a.f = f;
    unsigned r = a.u + 0x7FFF + ((a.u >> 16) & 1);   // round-to-nearest-even
    return (u16)(r >> 16);
}

// async global->LDS, 16B per lane; LDS dest = wave-uniform base + lane*16
static __device__ __forceinline__ void gload_lds16(const u16* g, u16* l) {
    __builtin_amdgcn_global_load_lds(
        (const __attribute__((address_space(1))) void*)g,
        (__attribute__((address_space(3))) void*)l, 16, 0, 0);
}

// ==================== fp32 -> bf16 conversion (plain) ====================
__global__ __launch_bounds__(256) void cvt_kernel(const float* __restrict__ s,
                                                  u16* __restrict__ d, int n) {
    int i = (blockIdx.x * 256 + threadIdx.x) * 8;
    if (i < n) {
        float4 a = *(const float4*)(s + i);
        float4 b = *(const float4*)(s + i + 4);
        u16 o[8] = { f2bf(a.x), f2bf(a.y), f2bf(a.z), f2bf(a.w),
                     f2bf(b.x), f2bf(b.y), f2bf(b.z), f2bf(b.w) };
        *(uint4*)(d + i) = *(const uint4*)o;
    }
}

// ============== fp32 -> bf16 with row/col zero padding ==============
__global__ __launch_bounds__(256) void cvt_pad_kernel(const float* __restrict__ s,
                                                      u16* __restrict__ d,
                                                      int R, int K, int Kp) {
    int chunk = blockIdx.x * 256 + threadIdx.x;
    int cpr = Kp >> 3;
    int r = chunk / cpr;
    int c = (chunk - r * cpr) << 3;
    u16 o[8] = {0, 0, 0, 0, 0, 0, 0, 0};
    if (r < R && c < K) {
        const float* p = s + (size_t)r * K + c;
        float4 a = *(const float4*)p;
        float4 b = *(const float4*)(p + 4);
        o[0] = f2bf(a.x); o[1] = f2bf(a.y); o[2] = f2bf(a.z); o[3] = f2bf(a.w);
        o[4] = f2bf(b.x); o[5] = f2bf(b.y); o[6] = f2bf(b.z); o[7] = f2bf(b.w);
    }
    *(uint4*)&d[(size_t)r * Kp + c] = *(const uint4*)o;
}

// ============================ LSTM (DPP-butterfly, no LDS) ============================
// One wave = 8 batch rows x 8 hidden units (lane = r*8 + u). Each lane computes all
// 4 gates of its unit for ALL THREE layers sequentially per time step. No LDS, no
// barriers, no flags, no ds_bpermute: the only cross-lane op is an XOR-butterfly
// broadcast of each layer's 8-wide h vector inside each 8-lane group, built from
// DPP quad_perm (xor1/2/3) + row_half_mirror (xor7) -> o[m] = v[lane ^ m], all VALU.
// Per-lane weights are loaded pre-permuted (W[G][u^m]) so the butterfly order is free.
// Recurrent partials Whh*h(t-1) for all 3 layers are computed at step top (off the
// serial path); critical path per layer = act -> bfly(2 DPP deep) -> 8-FMA dot.

template<int CTRL>
static __device__ __forceinline__ float dppf(float v) {
    union { float f; int i; } a, b;
    a.f = v;
    b.i = __builtin_amdgcn_update_dpp(0, a.i, CTRL, 0xF, 0xF, true);
    return b.f;
}

// o[m] = v from lane (lane ^ m), m = 0..7 (within each 8-lane group)
static __device__ __forceinline__ void bfly(float v, float* o) {
    o[0] = v;
    o[1] = dppf<0xB1>(v);        // quad_perm [1,0,3,2]  = xor1
    o[2] = dppf<0x4E>(v);        // quad_perm [2,3,0,1]  = xor2
    o[3] = dppf<0x1B>(v);        // quad_perm [3,2,1,0]  = xor3
    float m7 = dppf<0x141>(v);   // row_half_mirror      = xor7
    o[7] = m7;
    o[6] = dppf<0xB1>(m7);       // xor7^1 = xor6
    o[5] = dppf<0x4E>(m7);       // xor5
    o[4] = dppf<0x1B>(m7);       // xor4
}

static __device__ __forceinline__ float dot8(const float* w, const float* v, float s0) {
    float a = s0, b = 0.f;
#pragma unroll
    for (int m = 0; m < 4; ++m) a = __builtin_fmaf(w[m], v[m], a);
#pragma unroll
    for (int m = 4; m < 8; ++m) b = __builtin_fmaf(w[m], v[m], b);
    return a + b;
}

static __device__ __forceinline__ float sigm(float a) {
    return __fdividef(1.f, 1.f + __expf(-a));
}
// tanh(x) = 2*sigmoid(2x) - 1  (handles +/-inf saturation correctly)
static __device__ __forceinline__ float tns(float a) {
    return __builtin_fmaf(2.f, __fdividef(1.f, 1.f + __expf(-2.f * a)), -1.f);
}

__global__ __launch_bounds__(64) void lstm3_kernel(
    const float* __restrict__ x,
    const float* __restrict__ Wih1, const float* __restrict__ Whh1,
    const float* __restrict__ bih1, const float* __restrict__ bhh1,
    const float* __restrict__ Wih2, const float* __restrict__ Whh2,
    const float* __restrict__ bih2, const float* __restrict__ bhh2,
    const float* __restrict__ Wih3, const float* __restrict__ Whh3,
    const float* __restrict__ bih3, const float* __restrict__ bhh3,
    u16* __restrict__ A1)
{
    const int lane = threadIdx.x & 63;
    const int u = lane & 7;          // hidden unit this lane owns
    const int r = lane >> 3;         // batch row within block (0..7)
    const int b0 = blockIdx.x * 8;
    const int row = b0 + r;

    // zero the K padding columns of A1 (ws is poisoned each launch); 192 = 3*64 exact
    {
        int idx = lane;
#pragma unroll
        for (int it = 0; it < 3; ++it, idx += 64) {
            int rr = idx / 24, cc = idx - rr * 24;
            A1[(size_t)(b0 + rr) * K1P + K1V + cc] = 0;
        }
    }

    // per-lane weights, pre-permuted to butterfly order: slot m multiplies h[u^m]
    float wi1[4][8], wh1[4][8], wi2[4][8], wh2[4][8], wi3[4][8], wh3[4][8];
    float bs1[4], bs2[4], bs3[4];
#pragma unroll
    for (int g = 0; g < 4; ++g) {
        const int G = g * 8 + u;     // gate row (i:0-7, f:8-15, g:16-23, o:24-31)
        bs1[g] = bih1[G] + bhh1[G];
        bs2[g] = bih2[G] + bhh2[G];
        bs3[g] = bih3[G] + bhh3[G];
#pragma unroll
        for (int m = 0; m < 8; ++m) {
            const int k = u ^ m;
            wh1[g][m] = Whh1[G * 8 + k];
            wi1[g][m] = (k < 5) ? Wih1[G * 5 + k] : 0.f;   // zero-pad 5-wide input dot
            wi2[g][m] = Wih2[G * 8 + k];
            wh2[g][m] = Whh2[G * 8 + k];
            wi3[g][m] = Wih3[G * 8 + k];
            wh3[g][m] = Whh3[G * 8 + k];
        }
    }

    const float* xrow = x + (size_t)row * (T_SZ * 5);
    const int ux = (u < 5) ? u : 0;            // clamp: lanes u>=5 load a valid addr;
                                               // their xv slots hit zero weights
    u16* outp = A1 + (size_t)row * K1P;

    float h1v[8], h2v[8], h3v[8];
#pragma unroll
    for (int m = 0; m < 8; ++m) { h1v[m] = 0.f; h2v[m] = 0.f; h3v[m] = 0.f; }
    float c1 = 0.f, c2 = 0.f, c3 = 0.f;
    float xc = xrow[ux];                       // x(t=0)

#pragma unroll 1
    for (int t = 0; t < T_SZ; ++t) {
        const int tn = (t < T_SZ - 1) ? t + 1 : t;
        const float xn = xrow[tn * 5 + ux];    // prefetch next step's x

        // recurrent partials from h(t-1) — off the serial path
        float q1[4], q2[4], q3[4];
#pragma unroll
        for (int g = 0; g < 4; ++g) {
            q1[g] = dot8(wh1[g], h1v, bs1[g]);
            q2[g] = dot8(wh2[g], h2v, bs2[g]);
            q3[g] = dot8(wh3[g], h3v, bs3[g]);
        }

        float xv[8];
        bfly(xc, xv);

        // ---------------- L1 ----------------
#pragma unroll
        for (int g = 0; g < 4; ++g) q1[g] = dot8(wi1[g], xv, q1[g]);
        {
            float i = sigm(q1[0]), f = sigm(q1[1]), gg = tns(q1[2]), o = sigm(q1[3]);
            c1 = __builtin_fmaf(f, c1, i * gg);
            bfly(o * tns(c1), h1v);
        }
        // ---------------- L2 ----------------
#pragma unroll
        for (int g = 0; g < 4; ++g) q2[g] = dot8(wi2[g], h1v, q2[g]);
        {
            float i = sigm(q2[0]), f = sigm(q2[1]), gg = tns(q2[2]), o = sigm(q2[3]);
            c2 = __builtin_fmaf(f, c2, i * gg);
            bfly(o * tns(c2), h2v);
        }
        // ---------------- L3 ----------------
#pragma unroll
        for (int g = 0; g < 4; ++g) q3[g] = dot8(wi3[g], h2v, q3[g]);
        {
            float i = sigm(q3[0]), f = sigm(q3[1]), gg = tns(q3[2]), o = sigm(q3[3]);
            c3 = __builtin_fmaf(f, c3, i * gg);
            float h = o * tns(c3);
            bfly(h, h3v);
            outp[t * 8 + u] = f2bf(h);
        }
        xc = xn;
    }
}

// ============================ bf16 NT GEMM + bias + (ReLU) ============================
// C[m][n] = act( sum_k A[m][k]*B[n][k] + bias[n] ). 16x16x32 bf16 MFMA, BK=32,
// m97-style async staging: global_load_lds dwordx4, unpadded LDS (row = 32 u16).
template<int BM, int BN, bool RELU, bool NGUARD, bool OUTF32>
__global__ __launch_bounds__(256) void gemm_bt(
    const u16* __restrict__ A, int lda,
    const u16* __restrict__ B, int ldb,
    const float* __restrict__ bias,
    void* __restrict__ Cv, int ldc, int N, int K)
{
    constexpr int WM = BM / 2, WN = BN / 2;
    constexpr int TM = WM / 16, TN = WN / 16;
    __shared__ u16 As[BM * 32];
    __shared__ u16 Bs[BN * 32];

    const int tid = threadIdx.x;
    const int bm  = blockIdx.y * BM;
    const int bn  = blockIdx.x * BN;
    const int l   = tid & 63, w = tid >> 6;
    const int wr  = w >> 1, wc = w & 1;
    const int lr  = l & 15, q = l >> 4;
    const int lrow = l >> 2;            // staging: lane -> row within 16-row group
    const int lcol = (l & 3) << 3;      // staging: lane -> 8-elem chunk

    floatx4 acc[TM][TN];
#pragma unroll
    for (int i = 0; i < TM; ++i)
#pragma unroll
        for (int j = 0; j < TN; ++j) acc[i][j] = (floatx4){0.f, 0.f, 0.f, 0.f};

    const u16* Ab = A + (size_t)bm * lda;
    const u16* Bb = B + (size_t)bn * ldb;

    for (int k0 = 0; k0 < K; k0 += 32) {
#pragma unroll
        for (int i = 0; i < BM / 64; ++i) {
            int r0 = w * (BM / 4) + i * 16;
            gload_lds16(Ab + (size_t)(r0 + lrow) * lda + k0 + lcol, &As[r0 * 32]);
        }
#pragma unroll
        for (int i = 0; i < BN / 64; ++i) {
            int r0 = w * (BN / 4) + i * 16;
            gload_lds16(Bb + (size_t)(r0 + lrow) * ldb + k0 + lcol, &Bs[r0 * 32]);
        }
        __syncthreads();

        short8 fa[TM], fb[TN];
#pragma unroll
        for (int i = 0; i < TM; ++i)
            fa[i] = *(const short8*)&As[(wr * WM + i * 16 + lr) * 32 + q * 8];
#pragma unroll
        for (int j = 0; j < TN; ++j)
            fb[j] = *(const short8*)&Bs[(wc * WN + j * 16 + lr) * 32 + q * 8];
#pragma unroll
        for (int i = 0; i < TM; ++i)
#pragma unroll
            for (int j = 0; j < TN; ++j)
                acc[i][j] = __builtin_amdgcn_mfma_f32_16x16x32_bf16(fa[i], fb[j], acc[i][j], 0, 0, 0);
        __syncthreads();
    }

    // epilogue: C/D layout col = lane&15, row = (lane>>4)*4 + reg  [m89/m91]
#pragma unroll
    for (int j = 0; j < TN; ++j) {
        int n = bn + wc * WN + j * 16 + lr;
        bool nok = (!NGUARD) || (n < N);
        float bv = nok ? bias[n] : 0.f;
#pragma unroll
        for (int i = 0; i < TM; ++i) {
            int m0r = bm + wr * WM + i * 16 + q * 4;
#pragma unroll
            for (int r = 0; r < 4; ++r) {
                float vv = acc[i][j][r] + bv;
                if (RELU) vv = fmaxf(vv, 0.f);
                if (nok) {
                    size_t idx = (size_t)(m0r + r) * ldc + n;
                    if (OUTF32) ((float*)Cv)[idx] = vv;
                    else        ((u16*)Cv)[idx] = f2bf(vv);
                }
            }
        }
    }
}

// ============================ launch ============================
extern "C" void kernel_launch(void* const* d_in, const int* in_sizes, int n_in,
                              void* d_out, int out_size, void* d_ws, size_t ws_size,
                              hipStream_t stream)
{
    const float* x    = (const float*)d_in[0];
    const float* Wih1 = (const float*)d_in[1];
    const float* Whh1 = (const float*)d_in[2];
    const float* bih1 = (const float*)d_in[3];
    const float* bhh1 = (const float*)d_in[4];
    const float* Wih2 = (const float*)d_in[5];
    const float* Whh2 = (const float*)d_in[6];
    const float* bih2 = (const float*)d_in[7];
    const float* bhh2 = (const float*)d_in[8];
    const float* Wih3 = (const float*)d_in[9];
    const float* Whh3 = (const float*)d_in[10];
    const float* bih3 = (const float*)d_in[11];
    const float* bhh3 = (const float*)d_in[12];
    const float* W1 = (const float*)d_in[13];
    const float* b1 = (const float*)d_in[14];
    const float* W2 = (const float*)d_in[15];
    const float* b2 = (const float*)d_in[16];
    const float* W3 = (const float*)d_in[17];
    const float* b3 = (const float*)d_in[18];

    // ws layout (bf16 elems): A1[2048][4896], A2[2048][4096], A3[2048][1024],
    // W1b[4096][4896] (K-padded), W2b[1024][4096], W3b[640][1024] (row-padded). ~91 MB.
    u16* A1  = (u16*)d_ws;
    u16* A2  = A1  + (size_t)2048 * K1P;
    u16* A3  = A2  + (size_t)2048 * 4096;
    u16* W1b = A3  + (size_t)2048 * 1024;
    u16* W2b = W1b + (size_t)4096 * K1P;
    u16* W3b = W2b + (size_t)1024 * 4096;

    // weight conversions fp32 -> bf16 (zero-padded where needed)
    cvt_pad_kernel<<<9792, 256, 0, stream>>>(W1, W1b, 4096, K1V, K1P);
    cvt_kernel<<<2048, 256, 0, stream>>>(W2, W2b, 1024 * 4096);
    cvt_pad_kernel<<<320, 256, 0, stream>>>(W3, W3b, T_SZ, 1024, 1024);

    // LSTM: 1 wave per 8 batch rows, all 3 layers in-wave, DPP butterflies only
    lstm3_kernel<<<256, 64, 0, stream>>>(x, Wih1, Whh1, bih1, bhh1,
                                         Wih2, Whh2, bih2, bhh2,
                                         Wih3, Whh3, bih3, bhh3, A1);

    // L1: [2048,4896] x W1b[4096,4896] -> relu -> A2 [2048,4096]  (bf16 out)
    gemm_bt<128, 128, true, false, false><<<dim3(32, 16), 256, 0, stream>>>(
        A1, K1P, W1b, K1P, b1, A2, 4096, 4096, K1P);

    // L2: [2048,4096] x W2b[1024,4096] -> relu -> A3 [2048,1024]  (bf16 out)
    gemm_bt<64, 128, true, false, false><<<dim3(8, 32), 256, 0, stream>>>(
        A2, 4096, W2b, 4096, b2, A3, 1024, 1024, 4096);

    // L3: [2048,1024] x W3b[640,1024] -> d_out [2048,609]  (fp32 out, store N-guard)
    gemm_bt<64, 128, false, true, true><<<dim3(5, 32), 256, 0, stream>>>(
        A3, 1024, W3b, 1024, b3, d_out, T_SZ, T_SZ, 1024);
}

// Round 2
// 951.525 us; speedup vs baseline: 1.0590x; 1.0590x over previous
//
#include <hip/hip_runtime.h>
#include <hip/hip_bf16.h>

typedef __attribute__((ext_vector_type(8))) short short8;
typedef __attribute__((ext_vector_type(4))) float floatx4;
typedef __attribute__((ext_vector_type(2))) float f32x2;
typedef unsigned short u16;

#define T_SZ 609
#define K1V  4872   // valid K of flattened LSTM output (609*8)
#define K1P  4896   // padded to multiple of 32

static __device__ __forceinline__ u16 f2bf(float f) {
    union { float f; unsigned u; } a; a.f = f;
    unsigned r = a.u + 0x7FFF + ((a.u >> 16) & 1);   // round-to-nearest-even
    return (u16)(r >> 16);
}

// async global->LDS, 16B per lane; LDS dest = wave-uniform base + lane*16
static __device__ __forceinline__ void gload_lds16(const u16* g, u16* l) {
    __builtin_amdgcn_global_load_lds(
        (const __attribute__((address_space(1))) void*)g,
        (__attribute__((address_space(3))) void*)l, 16, 0, 0);
}

// ==================== fp32 -> bf16 conversion (plain) ====================
__global__ __launch_bounds__(256) void cvt_kernel(const float* __restrict__ s,
                                                  u16* __restrict__ d, int n) {
    int i = (blockIdx.x * 256 + threadIdx.x) * 8;
    if (i < n) {
        float4 a = *(const float4*)(s + i);
        float4 b = *(const float4*)(s + i + 4);
        u16 o[8] = { f2bf(a.x), f2bf(a.y), f2bf(a.z), f2bf(a.w),
                     f2bf(b.x), f2bf(b.y), f2bf(b.z), f2bf(b.w) };
        *(uint4*)(d + i) = *(const uint4*)o;
    }
}

// ============== fp32 -> bf16 with row/col zero padding ==============
__global__ __launch_bounds__(256) void cvt_pad_kernel(const float* __restrict__ s,
                                                      u16* __restrict__ d,
                                                      int R, int K, int Kp) {
    int chunk = blockIdx.x * 256 + threadIdx.x;
    int cpr = Kp >> 3;
    int r = chunk / cpr;
    int c = (chunk - r * cpr) << 3;
    u16 o[8] = {0, 0, 0, 0, 0, 0, 0, 0};
    if (r < R && c < K) {
        const float* p = s + (size_t)r * K + c;
        float4 a = *(const float4*)p;
        float4 b = *(const float4*)(p + 4);
        o[0] = f2bf(a.x); o[1] = f2bf(a.y); o[2] = f2bf(a.z); o[3] = f2bf(a.w);
        o[4] = f2bf(b.x); o[5] = f2bf(b.y); o[6] = f2bf(b.z); o[7] = f2bf(b.w);
    }
    *(uint4*)&d[(size_t)r * Kp + c] = *(const uint4*)o;
}

// ============================ LSTM (DPP-butterfly, skewed pipeline) ============================
// One wave = 8 batch rows x 8 hidden units (lane = r*8 + u). Each lane computes all
// 4 gates of its unit for all 3 layers. Cross-lane = DPP XOR-butterfly only (no LDS).
// SKEW: iteration t computes L1 step t, L2 step t-1, L3 step t-2. All gate dots read
// the PREVIOUS iteration's h arrays at the body top, so the three layer chains are
// independent within the body -> compiler interleaves them, critical path = 1 layer.
// L2/L3 state updates predicated for the warm-up (t>=1 / t>=2); tail runs harmlessly
// on clamped x (garbage flows only into never-consumed steps).
// __launch_bounds__(64,1): full 512-VGPR budget so all 6 weight arrays stay resident
// (round-1 failure: 136-VGPR cap -> weights rematerialized from global every step).
// Dots are f32x2 + elementwise_fma so LLVM can select v_pk_fma_f32 (2 FMA/instr).

template<int CTRL>
static __device__ __forceinline__ float dppf(float v) {
    union { float f; int i; } a, b;
    a.f = v;
    b.i = __builtin_amdgcn_update_dpp(0, a.i, CTRL, 0xF, 0xF, true);
    return b.f;
}

// o[m].x = v[lane^(2m)], o[m].y = v[lane^(2m+1)]  (within each 8-lane group)
static __device__ __forceinline__ void bfly2(float v, f32x2* o) {
    o[0] = (f32x2){v,              dppf<0xB1>(v)};   // xor0, xor1 (quad_perm 1,0,3,2)
    o[1] = (f32x2){dppf<0x4E>(v),  dppf<0x1B>(v)};   // xor2, xor3
    float m7 = dppf<0x141>(v);                       // row_half_mirror = xor7
    o[2] = (f32x2){dppf<0x1B>(m7), dppf<0x4E>(m7)};  // xor4 (=7^3), xor5 (=7^2)
    o[3] = (f32x2){dppf<0xB1>(m7), m7};              // xor6 (=7^1), xor7
}

static __device__ __forceinline__ float dot8(const f32x2* w, const f32x2* v, float s0) {
    f32x2 acc = (f32x2){s0, 0.f};
#pragma unroll
    for (int m = 0; m < 4; ++m) acc = __builtin_elementwise_fma(w[m], v[m], acc);
    return acc.x + acc.y;
}

static __device__ __forceinline__ float sigm(float a) {
    return __fdividef(1.f, 1.f + __expf(-a));
}
// tanh(x) = 2*sigmoid(2x) - 1  (saturates correctly at +/-inf)
static __device__ __forceinline__ float tns(float a) {
    return __builtin_fmaf(2.f, __fdividef(1.f, 1.f + __expf(-2.f * a)), -1.f);
}

__global__ __launch_bounds__(64, 1) void lstm3_kernel(
    const float* __restrict__ x,
    const float* __restrict__ Wih1, const float* __restrict__ Whh1,
    const float* __restrict__ bih1, const float* __restrict__ bhh1,
    const float* __restrict__ Wih2, const float* __restrict__ Whh2,
    const float* __restrict__ bih2, const float* __restrict__ bhh2,
    const float* __restrict__ Wih3, const float* __restrict__ Whh3,
    const float* __restrict__ bih3, const float* __restrict__ bhh3,
    u16* __restrict__ A1)
{
    const int lane = threadIdx.x & 63;
    const int u = lane & 7;          // hidden unit this lane owns
    const int r = lane >> 3;         // batch row within block (0..7)
    const int b0 = blockIdx.x * 8;
    const int row = b0 + r;

    // zero the K padding columns of A1 (ws is poisoned each launch); 192 = 3*64 exact
    {
        int idx = lane;
#pragma unroll
        for (int it = 0; it < 3; ++it, idx += 64) {
            int rr = idx / 24, cc = idx - rr * 24;
            A1[(size_t)(b0 + rr) * K1P + K1V + cc] = 0;
        }
    }

    // per-lane weights, pre-permuted to butterfly order: slot (m,comp) multiplies h[u^(2m+comp)]
    f32x2 wi1[4][4], wh1[4][4], wi2[4][4], wh2[4][4], wi3[4][4], wh3[4][4];
    float bs1[4], bs2[4], bs3[4];
#pragma unroll
    for (int g = 0; g < 4; ++g) {
        const int G = g * 8 + u;     // gate row (i:0-7, f:8-15, g:16-23, o:24-31)
        bs1[g] = bih1[G] + bhh1[G];
        bs2[g] = bih2[G] + bhh2[G];
        bs3[g] = bih3[G] + bhh3[G];
#pragma unroll
        for (int m = 0; m < 4; ++m) {
            const int ka = u ^ (2 * m), kb = ka ^ 1;
            wh1[g][m] = (f32x2){Whh1[G * 8 + ka], Whh1[G * 8 + kb]};
            wi1[g][m] = (f32x2){(ka < 5) ? Wih1[G * 5 + ka] : 0.f,
                                (kb < 5) ? Wih1[G * 5 + kb] : 0.f};
            wi2[g][m] = (f32x2){Wih2[G * 8 + ka], Wih2[G * 8 + kb]};
            wh2[g][m] = (f32x2){Whh2[G * 8 + ka], Whh2[G * 8 + kb]};
            wi3[g][m] = (f32x2){Wih3[G * 8 + ka], Wih3[G * 8 + kb]};
            wh3[g][m] = (f32x2){Whh3[G * 8 + ka], Whh3[G * 8 + kb]};
        }
    }

    const float* xrow = x + (size_t)row * (T_SZ * 5);
    const int ux = (u < 5) ? u : 0;            // lanes u>=5 load a valid addr; their
                                               // xv slots hit zero weights
    u16* outp = A1 + (size_t)row * K1P;

    f32x2 h1v[4], h2v[4], h3v[4];
#pragma unroll
    for (int m = 0; m < 4; ++m) {
        h1v[m] = (f32x2){0.f, 0.f}; h2v[m] = (f32x2){0.f, 0.f}; h3v[m] = (f32x2){0.f, 0.f};
    }
    float c1 = 0.f, c2 = 0.f, c3 = 0.f;
    float xc = xrow[ux];                       // x(t=0)

#pragma unroll 1
    for (int t = 0; t < T_SZ + 2; ++t) {
        const int tn = (t + 1 < T_SZ) ? t + 1 : T_SZ - 1;
        const float xn = xrow[tn * 5 + ux];    // prefetch next step's x (clamped)
        const bool s2 = (t >= 1), s3 = (t >= 2);

        // ---- all gate pre-activations read PREVIOUS-iteration h arrays: independent chains ----
        float q1[4], q2[4], q3[4];
#pragma unroll
        for (int g = 0; g < 4; ++g) {
            q1[g] = dot8(wh1[g], h1v, bs1[g]);   // h1(t-1)
            q2[g] = dot8(wh2[g], h2v, bs2[g]);   // h2(t-2)
            q3[g] = dot8(wh3[g], h3v, bs3[g]);   // h3(t-3)
        }
        f32x2 xv[4];
        bfly2(xc, xv);
#pragma unroll
        for (int g = 0; g < 4; ++g) {
            q1[g] = dot8(wi1[g], xv, q1[g]);     // x(t)
            q2[g] = dot8(wi2[g], h1v, q2[g]);    // h1(t-1): input to L2 step t-1
            q3[g] = dot8(wi3[g], h2v, q3[g]);    // h2(t-2): input to L3 step t-2
        }

        // ---------------- L1 finish (step t; tail garbage never consumed) ----------------
        {
            float i = sigm(q1[0]), f = sigm(q1[1]), gg = tns(q1[2]), o = sigm(q1[3]);
            c1 = __builtin_fmaf(f, c1, i * gg);
            bfly2(o * tns(c1), h1v);
        }
        // ---------------- L2 finish (step t-1; masked for t==0) ----------------
        {
            float i = sigm(q2[0]), f = sigm(q2[1]), gg = tns(q2[2]), o = sigm(q2[3]);
            float cn = __builtin_fmaf(f, c2, i * gg);
            float hs = o * tns(cn);
            c2 = s2 ? cn : 0.f;
            bfly2(s2 ? hs : 0.f, h2v);
        }
        // ---------------- L3 finish (step t-2; masked for t<2) ----------------
        {
            float i = sigm(q3[0]), f = sigm(q3[1]), gg = tns(q3[2]), o = sigm(q3[3]);
            float cn = __builtin_fmaf(f, c3, i * gg);
            float hs = o * tns(cn);
            c3 = s3 ? cn : 0.f;
            float ho = s3 ? hs : 0.f;
            bfly2(ho, h3v);
            if (s3) outp[(t - 2) * 8 + u] = f2bf(ho);
        }
        xc = xn;
    }
}

// ============================ bf16 NT GEMM + bias + (ReLU) ============================
// C[m][n] = act( sum_k A[m][k]*B[n][k] + bias[n] ). 16x16x32 bf16 MFMA, BK=32,
// m97-style async staging: global_load_lds dwordx4, unpadded LDS (row = 32 u16).
template<int BM, int BN, bool RELU, bool NGUARD, bool OUTF32>
__global__ __launch_bounds__(256) void gemm_bt(
    const u16* __restrict__ A, int lda,
    const u16* __restrict__ B, int ldb,
    const float* __restrict__ bias,
    void* __restrict__ Cv, int ldc, int N, int K)
{
    constexpr int WM = BM / 2, WN = BN / 2;
    constexpr int TM = WM / 16, TN = WN / 16;
    __shared__ u16 As[BM * 32];
    __shared__ u16 Bs[BN * 32];

    const int tid = threadIdx.x;
    const int bm  = blockIdx.y * BM;
    const int bn  = blockIdx.x * BN;
    const int l   = tid & 63, w = tid >> 6;
    const int wr  = w >> 1, wc = w & 1;
    const int lr  = l & 15, q = l >> 4;
    const int lrow = l >> 2;            // staging: lane -> row within 16-row group
    const int lcol = (l & 3) << 3;      // staging: lane -> 8-elem chunk

    floatx4 acc[TM][TN];
#pragma unroll
    for (int i = 0; i < TM; ++i)
#pragma unroll
        for (int j = 0; j < TN; ++j) acc[i][j] = (floatx4){0.f, 0.f, 0.f, 0.f};

    const u16* Ab = A + (size_t)bm * lda;
    const u16* Bb = B + (size_t)bn * ldb;

    for (int k0 = 0; k0 < K; k0 += 32) {
#pragma unroll
        for (int i = 0; i < BM / 64; ++i) {
            int r0 = w * (BM / 4) + i * 16;
            gload_lds16(Ab + (size_t)(r0 + lrow) * lda + k0 + lcol, &As[r0 * 32]);
        }
#pragma unroll
        for (int i = 0; i < BN / 64; ++i) {
            int r0 = w * (BN / 4) + i * 16;
            gload_lds16(Bb + (size_t)(r0 + lrow) * ldb + k0 + lcol, &Bs[r0 * 32]);
        }
        __syncthreads();

        short8 fa[TM], fb[TN];
#pragma unroll
        for (int i = 0; i < TM; ++i)
            fa[i] = *(const short8*)&As[(wr * WM + i * 16 + lr) * 32 + q * 8];
#pragma unroll
        for (int j = 0; j < TN; ++j)
            fb[j] = *(const short8*)&Bs[(wc * WN + j * 16 + lr) * 32 + q * 8];
#pragma unroll
        for (int i = 0; i < TM; ++i)
#pragma unroll
            for (int j = 0; j < TN; ++j)
                acc[i][j] = __builtin_amdgcn_mfma_f32_16x16x32_bf16(fa[i], fb[j], acc[i][j], 0, 0, 0);
        __syncthreads();
    }

    // epilogue: C/D layout col = lane&15, row = (lane>>4)*4 + reg  [m89/m91]
#pragma unroll
    for (int j = 0; j < TN; ++j) {
        int n = bn + wc * WN + j * 16 + lr;
        bool nok = (!NGUARD) || (n < N);
        float bv = nok ? bias[n] : 0.f;
#pragma unroll
        for (int i = 0; i < TM; ++i) {
            int m0r = bm + wr * WM + i * 16 + q * 4;
#pragma unroll
            for (int r = 0; r < 4; ++r) {
                float vv = acc[i][j][r] + bv;
                if (RELU) vv = fmaxf(vv, 0.f);
                if (nok) {
                    size_t idx = (size_t)(m0r + r) * ldc + n;
                    if (OUTF32) ((float*)Cv)[idx] = vv;
                    else        ((u16*)Cv)[idx] = f2bf(vv);
                }
            }
        }
    }
}

// ============================ launch ============================
extern "C" void kernel_launch(void* const* d_in, const int* in_sizes, int n_in,
                              void* d_out, int out_size, void* d_ws, size_t ws_size,
                              hipStream_t stream)
{
    const float* x    = (const float*)d_in[0];
    const float* Wih1 = (const float*)d_in[1];
    const float* Whh1 = (const float*)d_in[2];
    const float* bih1 = (const float*)d_in[3];
    const float* bhh1 = (const float*)d_in[4];
    const float* Wih2 = (const float*)d_in[5];
    const float* Whh2 = (const float*)d_in[6];
    const float* bih2 = (const float*)d_in[7];
    const float* bhh2 = (const float*)d_in[8];
    const float* Wih3 = (const float*)d_in[9];
    const float* Whh3 = (const float*)d_in[10];
    const float* bih3 = (const float*)d_in[11];
    const float* bhh3 = (const float*)d_in[12];
    const float* W1 = (const float*)d_in[13];
    const float* b1 = (const float*)d_in[14];
    const float* W2 = (const float*)d_in[15];
    const float* b2 = (const float*)d_in[16];
    const float* W3 = (const float*)d_in[17];
    const float* b3 = (const float*)d_in[18];

    // ws layout (bf16 elems): A1[2048][4896], A2[2048][4096], A3[2048][1024],
    // W1b[4096][4896] (K-padded), W2b[1024][4096], W3b[640][1024] (row-padded). ~91 MB.
    u16* A1  = (u16*)d_ws;
    u16* A2  = A1  + (size_t)2048 * K1P;
    u16* A3  = A2  + (size_t)2048 * 4096;
    u16* W1b = A3  + (size_t)2048 * 1024;
    u16* W2b = W1b + (size_t)4096 * K1P;
    u16* W3b = W2b + (size_t)1024 * 4096;

    // weight conversions fp32 -> bf16 (zero-padded where needed)
    cvt_pad_kernel<<<9792, 256, 0, stream>>>(W1, W1b, 4096, K1V, K1P);
    cvt_kernel<<<2048, 256, 0, stream>>>(W2, W2b, 1024 * 4096);
    cvt_pad_kernel<<<320, 256, 0, stream>>>(W3, W3b, T_SZ, 1024, 1024);

    // LSTM: 1 wave per 8 batch rows, all 3 layers skew-pipelined in-wave
    lstm3_kernel<<<256, 64, 0, stream>>>(x, Wih1, Whh1, bih1, bhh1,
                                         Wih2, Whh2, bih2, bhh2,
                                         Wih3, Whh3, bih3, bhh3, A1);

    // L1: [2048,4896] x W1b[4096,4896] -> relu -> A2 [2048,4096]  (bf16 out)
    gemm_bt<128, 128, true, false, false><<<dim3(32, 16), 256, 0, stream>>>(
        A1, K1P, W1b, K1P, b1, A2, 4096, 4096, K1P);

    // L2: [2048,4096] x W2b[1024,4096] -> relu -> A3 [2048,1024]  (bf16 out)
    gemm_bt<64, 128, true, false, false><<<dim3(8, 32), 256, 0, stream>>>(
        A2, 4096, W2b, 4096, b2, A3, 1024, 1024, 4096);

    // L3: [2048,1024] x W3b[640,1024] -> d_out [2048,609]  (fp32 out, store N-guard)
    gemm_bt<64, 128, false, true, true><<<dim3(5, 32), 256, 0, stream>>>(
        A3, 1024, W3b, 1024, b3, d_out, T_SZ, T_SZ, 1024);
}